// Round 1
// baseline (740.647 us; speedup 1.0000x reference)
//
#include <hip/hip_runtime.h>
#include <hip/hip_bf16.h>

#define NF 128

// ---------------- CSR build ----------------

__global__ void k_zero(int* __restrict__ p, int n) {
  int i = blockIdx.x * blockDim.x + threadIdx.x;
  if (i < n) p[i] = 0;
}

__global__ void k_hist(const int* __restrict__ dst, int* __restrict__ cnt, int E) {
  int i = blockIdx.x * blockDim.x + threadIdx.x;
  if (i < E) atomicAdd(&cnt[dst[i]], 1);
}

// single-block chunked exclusive scan: off[0]=0, off[i+1]=sum(deg[0..i])
__global__ __launch_bounds__(1024) void k_scan(const int* __restrict__ deg,
                                               int* __restrict__ off, int n) {
  __shared__ int warp_sums[16];
  __shared__ int chunk_base;
  int tid = threadIdx.x;
  int lane = tid & 63, wid = tid >> 6;
  if (tid == 0) chunk_base = 0;
  __syncthreads();
  for (int base = 0; base < n; base += 1024) {
    int i = base + tid;
    int v = (i < n) ? deg[i] : 0;
    int s = v;
    #pragma unroll
    for (int d = 1; d < 64; d <<= 1) {
      int t = __shfl_up(s, d, 64);
      if (lane >= d) s += t;
    }
    if (lane == 63) warp_sums[wid] = s;
    __syncthreads();
    if (wid == 0 && lane < 16) {
      int ws = warp_sums[lane];
      #pragma unroll
      for (int d = 1; d < 16; d <<= 1) {
        int t = __shfl_up(ws, d, 64);
        if (lane >= d) ws += t;
      }
      warp_sums[lane] = ws;
    }
    __syncthreads();
    int wave_off = (wid > 0) ? warp_sums[wid - 1] : 0;
    int incl = s + wave_off + chunk_base;
    if (i < n) off[i + 1] = incl;
    __syncthreads();                 // all reads of warp_sums done
    if (tid == 0) chunk_base += warp_sums[15];
    __syncthreads();                 // chunk_base visible, warp_sums reusable
  }
  if (tid == 0) off[0] = 0;
}

__global__ void k_fill(const int* __restrict__ src, const int* __restrict__ dst,
                       const int* __restrict__ off, int* __restrict__ cur,
                       int* __restrict__ esrc, int E) {
  int i = blockIdx.x * blockDim.x + threadIdx.x;
  if (i < E) {
    int d = dst[i];
    int p = off[d] + atomicAdd(&cur[d], 1);
    esrc[p] = src[i];
  }
}

// ---------------- GEMM: C = act(A0@W0 [+ A1@W1] + b), all [*,128]x[128,128] ----------------
// block: 256 threads, BM=64 rows. LDS: half of W (64x128) + A tile (64x64, padded).
// microtile per thread: 4 rows x 8 cols.

template <bool RELU, int NMAT>
__global__ __launch_bounds__(256) void k_gemm(
    const float* __restrict__ A0, const float* __restrict__ W0,
    const float* __restrict__ A1, const float* __restrict__ W1,
    const float* __restrict__ bias, float* __restrict__ C, int N) {
  __shared__ float Ws[64][NF];      // 32 KB
  __shared__ float As[64][68];      // 17.4 KB, padded stride (16B-aligned rows)

  const int tid = threadIdx.x;
  const int base = blockIdx.x * 64;
  const int tc = tid & 15;          // cols tc*8 .. tc*8+7
  const int tr = tid >> 4;          // rows tr*4 .. tr*4+3

  float acc[4][8];
  #pragma unroll
  for (int r = 0; r < 4; ++r)
    #pragma unroll
    for (int c = 0; c < 8; ++c) acc[r][c] = 0.f;

  #pragma unroll 1
  for (int mat = 0; mat < NMAT; ++mat) {
    const float* __restrict__ A = (mat == 0) ? A0 : A1;
    const float* __restrict__ W = (mat == 0) ? W0 : W1;
    #pragma unroll 1
    for (int k0 = 0; k0 < NF; k0 += 64) {
      __syncthreads();
      // stage W[k0..k0+63][:] -> Ws   (2048 float4, 8 per thread)
      for (int t = tid; t < 64 * 32; t += 256) {
        int k = t >> 5, cq = t & 31;
        float4 v = *(const float4*)(W + (size_t)(k0 + k) * NF + cq * 4);
        *(float4*)&Ws[k][cq * 4] = v;
      }
      // stage A[base..base+63][k0..k0+63] -> As  (1024 float4, 4 per thread)
      for (int t = tid; t < 64 * 16; t += 256) {
        int row = t >> 4, kq = t & 15;
        int grow = base + row;
        float4 v = make_float4(0.f, 0.f, 0.f, 0.f);
        if (grow < N) v = *(const float4*)(A + (size_t)grow * NF + k0 + kq * 4);
        *(float4*)&As[row][kq * 4] = v;
      }
      __syncthreads();
      #pragma unroll 8
      for (int k = 0; k < 64; ++k) {
        float av[4];
        #pragma unroll
        for (int r = 0; r < 4; ++r) av[r] = As[tr * 4 + r][k];
        float4 w0 = *(const float4*)&Ws[k][tc * 8];
        float4 w1 = *(const float4*)&Ws[k][tc * 8 + 4];
        float wv[8] = {w0.x, w0.y, w0.z, w0.w, w1.x, w1.y, w1.z, w1.w};
        #pragma unroll
        for (int r = 0; r < 4; ++r)
          #pragma unroll
          for (int c = 0; c < 8; ++c)
            acc[r][c] = fmaf(av[r], wv[c], acc[r][c]);
      }
    }
  }

  float4 bv0 = *(const float4*)(bias + tc * 8);
  float4 bv1 = *(const float4*)(bias + tc * 8 + 4);
  float bb[8] = {bv0.x, bv0.y, bv0.z, bv0.w, bv1.x, bv1.y, bv1.z, bv1.w};
  #pragma unroll
  for (int r = 0; r < 4; ++r) {
    int grow = base + tr * 4 + r;
    if (grow >= N) continue;
    float o[8];
    #pragma unroll
    for (int c = 0; c < 8; ++c) {
      o[c] = acc[r][c] + bb[c];
      if (RELU) o[c] = fmaxf(o[c], 0.f);
    }
    *(float4*)(C + (size_t)grow * NF + tc * 8)     = make_float4(o[0], o[1], o[2], o[3]);
    *(float4*)(C + (size_t)grow * NF + tc * 8 + 4) = make_float4(o[4], o[5], o[6], o[7]);
  }
}

// ---------------- gather-max: one wave per dst node ----------------

__global__ __launch_bounds__(256) void k_gather_max(
    const float* __restrict__ Y, const int* __restrict__ off,
    const int* __restrict__ esrc, float* __restrict__ AGG, int N) {
  int w = (blockIdx.x * 256 + threadIdx.x) >> 6;
  int lane = threadIdx.x & 63;
  if (w >= N) return;
  int s = __builtin_amdgcn_readfirstlane(off[w]);
  int e = __builtin_amdgcn_readfirstlane(off[w + 1]);
  float2 acc = make_float2(0.f, 0.f);   // relu output >= 0, so 0 == empty-segment fill
  int i = s;
  for (; i + 1 < e; i += 2) {
    int u0 = __builtin_amdgcn_readfirstlane(esrc[i]);
    int u1 = __builtin_amdgcn_readfirstlane(esrc[i + 1]);
    float2 v0 = *(const float2*)(Y + (size_t)u0 * NF + lane * 2);
    float2 v1 = *(const float2*)(Y + (size_t)u1 * NF + lane * 2);
    acc.x = fmaxf(acc.x, fmaxf(v0.x, v1.x));
    acc.y = fmaxf(acc.y, fmaxf(v0.y, v1.y));
  }
  if (i < e) {
    int u = __builtin_amdgcn_readfirstlane(esrc[i]);
    float2 v = *(const float2*)(Y + (size_t)u * NF + lane * 2);
    acc.x = fmaxf(acc.x, v.x);
    acc.y = fmaxf(acc.y, v.y);
  }
  *(float2*)(AGG + (size_t)w * NF + lane * 2) = acc;
}

// ---------------- row L2-normalize + relu: one wave per row ----------------

__global__ __launch_bounds__(256) void k_l2norm_relu(
    const float* __restrict__ T, float* __restrict__ O, int N) {
  int w = (blockIdx.x * 256 + threadIdx.x) >> 6;
  int lane = threadIdx.x & 63;
  if (w >= N) return;
  float2 t = *(const float2*)(T + (size_t)w * NF + lane * 2);
  float ss = t.x * t.x + t.y * t.y;
  #pragma unroll
  for (int d = 32; d > 0; d >>= 1) ss += __shfl_xor(ss, d, 64);
  float nrm = fmaxf(sqrtf(ss), 1e-12f);
  float inv = 1.f / nrm;
  float2 o = make_float2(fmaxf(t.x * inv, 0.f), fmaxf(t.y * inv, 0.f));
  *(float2*)(O + (size_t)w * NF + lane * 2) = o;
}

// ---------------- launch ----------------

extern "C" void kernel_launch(void* const* d_in, const int* in_sizes, int n_in,
                              void* d_out, int out_size, void* d_ws, size_t ws_size,
                              hipStream_t stream) {
  const float* x   = (const float*)d_in[0];
  const int*   src = (const int*)d_in[1];
  const int*   dst = (const int*)d_in[2];
  const float* Wp1 = (const float*)d_in[3];
  const float* bp1 = (const float*)d_in[4];
  const float* Ws1 = (const float*)d_in[5];
  const float* Wn1 = (const float*)d_in[6];
  const float* b1  = (const float*)d_in[7];
  const float* Wp2 = (const float*)d_in[8];
  const float* bp2 = (const float*)d_in[9];
  const float* Ws2 = (const float*)d_in[10];
  const float* Wn2 = (const float*)d_in[11];
  const float* b2  = (const float*)d_in[12];
  float* out = (float*)d_out;

  const int N = in_sizes[0] / NF;
  const int E = in_sizes[1];

  char* ws = (char*)d_ws;
  int* off  = (int*)ws;  ws += (size_t)(N + 1) * sizeof(int);
  int* cur  = (int*)ws;  ws += (size_t)N * sizeof(int);
  int* esrc = (int*)ws;  ws += (size_t)E * sizeof(int);
  ws = (char*)(((size_t)ws + 255) & ~(size_t)255);
  float* Y   = (float*)ws;  ws += (size_t)N * NF * sizeof(float);
  float* AGG = (float*)ws;  ws += (size_t)N * NF * sizeof(float);
  float* H   = (float*)ws;  ws += (size_t)N * NF * sizeof(float);

  const int gN  = (N + 255) / 256;
  const int gE  = (E + 255) / 256;
  const int gG  = (N + 63) / 64;    // gemm blocks (BM=64)
  const int gRW = (N + 3) / 4;      // wave-per-row kernels, 4 waves/block

  // CSR by dst (graph identical for both layers)
  k_zero<<<gN, 256, 0, stream>>>(cur, N);
  k_hist<<<gE, 256, 0, stream>>>(dst, cur, E);
  k_scan<<<1, 1024, 0, stream>>>(cur, off, N);
  k_zero<<<gN, 256, 0, stream>>>(cur, N);
  k_fill<<<gE, 256, 0, stream>>>(src, dst, off, cur, esrc, E);

  // ---- layer 1 ----
  k_gemm<true, 1><<<gG, 256, 0, stream>>>(x, Wp1, nullptr, nullptr, bp1, Y, N);
  k_gather_max<<<gRW, 256, 0, stream>>>(Y, off, esrc, AGG, N);
  k_gemm<false, 2><<<gG, 256, 0, stream>>>(x, Ws1, AGG, Wn1, b1, Y, N);
  k_l2norm_relu<<<gRW, 256, 0, stream>>>(Y, H, N);

  // ---- layer 2 ----
  k_gemm<true, 1><<<gG, 256, 0, stream>>>(H, Wp2, nullptr, nullptr, bp2, Y, N);
  k_gather_max<<<gRW, 256, 0, stream>>>(Y, off, esrc, AGG, N);
  k_gemm<false, 2><<<gG, 256, 0, stream>>>(H, Ws2, AGG, Wn2, b2, Y, N);
  k_l2norm_relu<<<gRW, 256, 0, stream>>>(Y, out, N);
}

// Round 2
// 349.618 us; speedup vs baseline: 2.1184x; 2.1184x over previous
//
#include <hip/hip_runtime.h>
#include <hip/hip_bf16.h>

#define NF 128

typedef __attribute__((ext_vector_type(8))) short bf8;
typedef __attribute__((ext_vector_type(4))) float f4;

static __device__ __forceinline__ unsigned short f2bf(float f) {
  unsigned u = __builtin_bit_cast(unsigned, f);
  u = u + 0x7FFF + ((u >> 16) & 1);            // RNE
  return (unsigned short)(u >> 16);
}
static __device__ __forceinline__ float bf2f(unsigned short s) {
  unsigned u = ((unsigned)s) << 16;
  return __builtin_bit_cast(float, u);
}

// ---------------- fp32 -> bf16 convert (X), also zeroes bucket counters ----------------

__global__ void k_convX(const float* __restrict__ A, unsigned short* __restrict__ B,
                        long long nelem, int* __restrict__ bcnt, int nb) {
  long long i = (long long)(blockIdx.x * blockDim.x + threadIdx.x) * 8;
  if (blockIdx.x == 0 && (int)threadIdx.x < nb) bcnt[threadIdx.x] = 0;
  if (i + 8 > nelem) return;
  float4 a = *(const float4*)(A + i);
  float4 b = *(const float4*)(A + i + 4);
  uint4 o;
  o.x = f2bf(a.x) | ((unsigned)f2bf(a.y) << 16);
  o.y = f2bf(a.z) | ((unsigned)f2bf(a.w) << 16);
  o.z = f2bf(b.x) | ((unsigned)f2bf(b.y) << 16);
  o.w = f2bf(b.z) | ((unsigned)f2bf(b.w) << 16);
  *(uint4*)(B + i) = o;
}

// ---------------- pack 6 weight matrices [128][128] f32 -> B-fragment-ordered bf16 ----------------
// layout: chunk c = t*4+kk (t=n-tile 0..7, kk=k-step 0..3); unit u = c*64 + lane; 8 bf16 per unit:
//   elem j = W[kk*32 + (lane>>4)*8 + j][t*16 + (lane&15)]

__global__ void k_packW(const float* W0, const float* W1, const float* W2,
                        const float* W3, const float* W4, const float* W5,
                        unsigned short* __restrict__ out) {
  int gid = blockIdx.x * blockDim.x + threadIdx.x;    // one unit (8 elems) per thread
  int m = gid >> 11;                                   // 2048 units per matrix
  int u = gid & 2047;
  if (m >= 6) return;
  const float* W = (m == 0) ? W0 : (m == 1) ? W1 : (m == 2) ? W2
                 : (m == 3) ? W3 : (m == 4) ? W4 : W5;
  int l = u & 63, c = u >> 6;
  int kk = c & 3, t = c >> 2;
  int kb = kk * 32 + ((l >> 4) << 3);
  int n = t * 16 + (l & 15);
  unsigned short* o = out + (size_t)m * 2048 * 8 + (size_t)u * 8;
  #pragma unroll
  for (int j = 0; j < 8; ++j) o[j] = f2bf(W[(size_t)(kb + j) * NF + n]);
}

// ---------------- CSR build: bucket(256 dsts) 2-pass sort ----------------

#define TILE_B 8192

__global__ __launch_bounds__(256) void k_bhist(const int* __restrict__ dst,
                                               int* __restrict__ bcnt, int E) {
  __shared__ int h[256];
  int tid = threadIdx.x;
  h[tid] = 0;
  __syncthreads();
  int t0 = blockIdx.x * TILE_B;
  int tend = min(E, t0 + TILE_B);
  for (int i = t0 + tid; i < tend; i += 256) atomicAdd(&h[dst[i] >> 8], 1);
  __syncthreads();
  if (h[tid] > 0) atomicAdd(&bcnt[tid], h[tid]);
}

__global__ __launch_bounds__(256) void k_bscan(const int* __restrict__ bcnt,
                                               int* __restrict__ boff,
                                               int* __restrict__ cursors,
                                               int* __restrict__ off,
                                               int nb, int N, int E) {
  __shared__ int sc[256];
  int tid = threadIdx.x;
  int v = (tid < nb) ? bcnt[tid] : 0;
  sc[tid] = v;
  __syncthreads();
  for (int d = 1; d < 256; d <<= 1) {
    int t = (tid >= d) ? sc[tid - d] : 0;
    __syncthreads();
    sc[tid] += t;
    __syncthreads();
  }
  if (tid < nb) {
    boff[tid + 1] = sc[tid];
    cursors[tid] = sc[tid] - v;
  }
  if (tid == 0) { boff[0] = 0; off[N] = E; }
}

// pass B: tile-local counting sort by bucket, write bucket-contiguous runs to tmp
// tmp entry: (src << 8) | (dst & 255)
__global__ __launch_bounds__(256) void k_binB(const int* __restrict__ src,
                                              const int* __restrict__ dst,
                                              int* __restrict__ cursors,
                                              unsigned* __restrict__ tmp, int E) {
  __shared__ int h[256], sc[256], gb[256], lc[256];
  __shared__ unsigned sorted[TILE_B];
  int tid = threadIdx.x;
  int t0 = blockIdx.x * TILE_B;
  int tcnt = min(E - t0, TILE_B);
  if (tcnt <= 0) return;
  h[tid] = 0;
  __syncthreads();
  for (int i = tid; i < tcnt; i += 256) atomicAdd(&h[dst[t0 + i] >> 8], 1);
  __syncthreads();
  int v = h[tid];
  sc[tid] = v;
  __syncthreads();
  for (int d = 1; d < 256; d <<= 1) {
    int t = (tid >= d) ? sc[tid - d] : 0;
    __syncthreads();
    sc[tid] += t;
    __syncthreads();
  }
  lc[tid] = 0;
  gb[tid] = (v > 0) ? atomicAdd(&cursors[tid], v) : 0;
  __syncthreads();
  for (int i = tid; i < tcnt; i += 256) {
    int d = dst[t0 + i];
    int s = src[t0 + i];
    int b = d >> 8;
    int p = (sc[b] - h[b]) + atomicAdd(&lc[b], 1);
    sorted[p] = ((unsigned)s << 8) | (unsigned)(d & 255);
  }
  __syncthreads();
  for (int i = tid; i < tcnt; i += 256) {
    int lo = 0, hi = 255;                 // find first b with sc[b] > i
    while (lo < hi) { int mid = (lo + hi) >> 1; if (sc[mid] > i) hi = mid; else lo = mid + 1; }
    int b = lo;
    tmp[gb[b] + (i - (sc[b] - h[b]))] = sorted[i];
  }
}

// pass C: per-bucket CSR in LDS, coalesced flush; also writes off[]
#define CSR_CAP 15360

__global__ __launch_bounds__(256) void k_binC(const unsigned* __restrict__ tmp,
                                              const int* __restrict__ boff,
                                              int* __restrict__ off,
                                              int* __restrict__ esrc, int N) {
  __shared__ int lh[256], ls[256], lcur[256];
  __shared__ int csr[CSR_CAP];
  int tid = threadIdx.x;
  int b = blockIdx.x;
  int base = b << 8;
  int beg = boff[b], end = boff[b + 1];
  int cnt = end - beg;
  lh[tid] = 0;
  __syncthreads();
  for (int i = beg + tid; i < end; i += 256) atomicAdd(&lh[tmp[i] & 255], 1);
  __syncthreads();
  int v = lh[tid];
  ls[tid] = v;
  __syncthreads();
  for (int d = 1; d < 256; d <<= 1) {
    int t = (tid >= d) ? ls[tid - d] : 0;
    __syncthreads();
    ls[tid] += t;
    __syncthreads();
  }
  int excl = ls[tid] - v;
  if (base + tid < N) off[base + tid] = beg + excl;
  lcur[tid] = 0;
  __syncthreads();
  if (cnt <= CSR_CAP) {
    for (int i = beg + tid; i < end; i += 256) {
      unsigned e = tmp[i];
      int dl = (int)(e & 255);
      int p = (ls[dl] - lh[dl]) + atomicAdd(&lcur[dl], 1);
      csr[p] = (int)(e >> 8);
    }
    __syncthreads();
    for (int i = tid; i < cnt; i += 256) esrc[beg + i] = csr[i];
  } else {                                  // overflow fallback (never for this data)
    for (int i = beg + tid; i < end; i += 256) {
      unsigned e = tmp[i];
      int dl = (int)(e & 255);
      int p = (ls[dl] - lh[dl]) + atomicAdd(&lcur[dl], 1);
      esrc[beg + p] = (int)(e >> 8);
    }
  }
}

// ---------------- MFMA GEMM: C = epilogue(A0@W0 [+ A1@W1] + bias) ----------------
// 256 thr = 4 waves; block computes 64 rows x 128 cols; wave w -> rows w*16..w*16+15.
// OUT_MODE: 0 = relu -> bf16   1 = l2norm+relu -> bf16   2 = l2norm+relu -> fp32

template <int NMAT, int OUT_MODE>
__global__ __launch_bounds__(256) void k_gemm(
    const unsigned short* __restrict__ A0, const unsigned short* __restrict__ P0,
    const unsigned short* __restrict__ A1, const unsigned short* __restrict__ P1,
    const float* __restrict__ bias, void* __restrict__ Cout, int M) {
  int tid = threadIdx.x, w = tid >> 6, lane = tid & 63;
  int r0 = lane & 15, g = lane >> 4;
  int rowbase = blockIdx.x * 64 + w * 16;
  int arow = min(rowbase + r0, M - 1);     // clamped load row; stores guarded

  f4 acc[8];
  #pragma unroll
  for (int t = 0; t < 8; ++t) acc[t] = (f4){0.f, 0.f, 0.f, 0.f};

  #pragma unroll
  for (int mat = 0; mat < NMAT; ++mat) {
    const unsigned short* A = (mat == 0) ? A0 : A1;
    const unsigned short* P = (mat == 0) ? P0 : P1;
    const bf8* Ar = (const bf8*)(A + (size_t)arow * NF);
    const bf8* Pp = (const bf8*)P;
    #pragma unroll
    for (int kk = 0; kk < 4; ++kk) {
      bf8 a = Ar[kk * 4 + g];
      #pragma unroll
      for (int t = 0; t < 8; ++t) {
        bf8 b = Pp[(size_t)(t * 4 + kk) * 64 + lane];
        acc[t] = __builtin_amdgcn_mfma_f32_16x16x32_bf16(a, b, acc[t], 0, 0, 0);
      }
    }
  }

  float bb[8];
  #pragma unroll
  for (int t = 0; t < 8; ++t) bb[t] = bias[t * 16 + r0];

  float val[8][4];
  #pragma unroll
  for (int t = 0; t < 8; ++t)
    #pragma unroll
    for (int i = 0; i < 4; ++i) val[t][i] = acc[t][i] + bb[t];

  if (OUT_MODE == 0) {
    unsigned short* Y = (unsigned short*)Cout;
    #pragma unroll
    for (int i = 0; i < 4; ++i) {
      int row = rowbase + g * 4 + i;
      if (row >= M) continue;
      #pragma unroll
      for (int t = 0; t < 8; ++t)
        Y[(size_t)row * NF + t * 16 + r0] = f2bf(fmaxf(val[t][i], 0.f));
    }
  } else {
    float ss[4] = {0.f, 0.f, 0.f, 0.f};
    #pragma unroll
    for (int i = 0; i < 4; ++i)
      #pragma unroll
      for (int t = 0; t < 8; ++t) ss[i] += val[t][i] * val[t][i];
    #pragma unroll
    for (int d = 1; d < 16; d <<= 1)
      #pragma unroll
      for (int i = 0; i < 4; ++i) ss[i] += __shfl_xor(ss[i], d, 64);
    float inv[4];
    #pragma unroll
    for (int i = 0; i < 4; ++i) inv[i] = 1.f / fmaxf(sqrtf(ss[i]), 1e-12f);
    if (OUT_MODE == 1) {
      unsigned short* H = (unsigned short*)Cout;
      #pragma unroll
      for (int i = 0; i < 4; ++i) {
        int row = rowbase + g * 4 + i;
        if (row >= M) continue;
        #pragma unroll
        for (int t = 0; t < 8; ++t)
          H[(size_t)row * NF + t * 16 + r0] = f2bf(fmaxf(val[t][i] * inv[i], 0.f));
      }
    } else {
      float* O = (float*)Cout;
      #pragma unroll
      for (int i = 0; i < 4; ++i) {
        int row = rowbase + g * 4 + i;
        if (row >= M) continue;
        #pragma unroll
        for (int t = 0; t < 8; ++t)
          O[(size_t)row * NF + t * 16 + r0] = fmaxf(val[t][i] * inv[i], 0.f);
      }
    }
  }
}

// ---------------- gather-max over in-edges (bf16 rows), one wave per dst ----------------

__global__ __launch_bounds__(256) void k_gather_max(
    const unsigned short* __restrict__ Y, const int* __restrict__ off,
    const int* __restrict__ esrc, unsigned short* __restrict__ AGG, int N) {
  int w = (blockIdx.x * 256 + threadIdx.x) >> 6;
  int lane = threadIdx.x & 63;
  if (w >= N) return;
  int s = __builtin_amdgcn_readfirstlane(off[w]);
  int e = __builtin_amdgcn_readfirstlane(off[w + 1]);
  float ax = 0.f, ay = 0.f;                 // relu output >= 0 -> 0 == empty fill
  int i = s;
  for (; i + 1 < e; i += 2) {
    int u0 = __builtin_amdgcn_readfirstlane(esrc[i]);
    int u1 = __builtin_amdgcn_readfirstlane(esrc[i + 1]);
    unsigned v0 = *(const unsigned*)(Y + (size_t)u0 * NF + lane * 2);
    unsigned v1 = *(const unsigned*)(Y + (size_t)u1 * NF + lane * 2);
    float f0x = __builtin_bit_cast(float, v0 << 16);
    float f0y = __builtin_bit_cast(float, v0 & 0xFFFF0000u);
    float f1x = __builtin_bit_cast(float, v1 << 16);
    float f1y = __builtin_bit_cast(float, v1 & 0xFFFF0000u);
    ax = fmaxf(ax, fmaxf(f0x, f1x));
    ay = fmaxf(ay, fmaxf(f0y, f1y));
  }
  if (i < e) {
    int u = __builtin_amdgcn_readfirstlane(esrc[i]);
    unsigned v = *(const unsigned*)(Y + (size_t)u * NF + lane * 2);
    ax = fmaxf(ax, __builtin_bit_cast(float, v << 16));
    ay = fmaxf(ay, __builtin_bit_cast(float, v & 0xFFFF0000u));
  }
  unsigned o = (unsigned)f2bf(ax) | ((unsigned)f2bf(ay) << 16);
  *(unsigned*)(AGG + (size_t)w * NF + lane * 2) = o;
}

// ---------------- launch ----------------

extern "C" void kernel_launch(void* const* d_in, const int* in_sizes, int n_in,
                              void* d_out, int out_size, void* d_ws, size_t ws_size,
                              hipStream_t stream) {
  const float* x   = (const float*)d_in[0];
  const int*   src = (const int*)d_in[1];
  const int*   dst = (const int*)d_in[2];
  const float* Wp1 = (const float*)d_in[3];
  const float* bp1 = (const float*)d_in[4];
  const float* Ws1 = (const float*)d_in[5];
  const float* Wn1 = (const float*)d_in[6];
  const float* b1  = (const float*)d_in[7];
  const float* Wp2 = (const float*)d_in[8];
  const float* bp2 = (const float*)d_in[9];
  const float* Ws2 = (const float*)d_in[10];
  const float* Wn2 = (const float*)d_in[11];
  const float* b2  = (const float*)d_in[12];
  float* out = (float*)d_out;

  const int N = in_sizes[0] / NF;
  const int E = in_sizes[1];
  const int NB = (N + 255) >> 8;           // 256-dst buckets

  char* ws = (char*)d_ws;
  auto carve = [&](size_t bytes) { char* p = ws; ws += (bytes + 255) & ~(size_t)255; return p; };
  unsigned short* Xb    = (unsigned short*)carve((size_t)N * NF * 2);
  unsigned short* Yb    = (unsigned short*)carve((size_t)N * NF * 2);
  unsigned short* AGGb  = (unsigned short*)carve((size_t)N * NF * 2);
  unsigned short* Hb    = (unsigned short*)carve((size_t)N * NF * 2);
  unsigned short* Wpack = (unsigned short*)carve((size_t)6 * NF * NF * 2);
  int* off     = (int*)carve((size_t)(N + 1) * 4);
  int* bcnt    = (int*)carve((size_t)NB * 4);
  int* boff    = (int*)carve((size_t)(NB + 1) * 4);
  int* cursors = (int*)carve((size_t)NB * 4);
  unsigned* tmp = (unsigned*)carve((size_t)E * 4);
  int* esrc    = (int*)carve((size_t)E * 4);

  unsigned short* Pp1 = Wpack + 0 * NF * NF;
  unsigned short* Ps1 = Wpack + 1 * NF * NF;
  unsigned short* Pn1 = Wpack + 2 * NF * NF;
  unsigned short* Pp2 = Wpack + 3 * NF * NF;
  unsigned short* Ps2 = Wpack + 4 * NF * NF;
  unsigned short* Pn2 = Wpack + 5 * NF * NF;

  const long long nelX = (long long)N * NF;
  const int gConv = (int)((nelX / 8 + 255) / 256);
  const int gPack = (6 * 2048 + 255) / 256;
  const int gTile = (E + TILE_B - 1) / TILE_B;
  const int gG    = (N + 63) / 64;
  const int gRW   = (N + 3) / 4;

  // prep
  k_convX<<<gConv, 256, 0, stream>>>(x, Xb, nelX, bcnt, NB);
  k_packW<<<gPack, 256, 0, stream>>>(Wp1, Ws1, Wn1, Wp2, Ws2, Wn2, Wpack);

  // CSR by dst
  k_bhist<<<gTile, 256, 0, stream>>>(dst, bcnt, E);
  k_bscan<<<1, 256, 0, stream>>>(bcnt, boff, cursors, off, NB, N, E);
  k_binB<<<gTile, 256, 0, stream>>>(src, dst, cursors, tmp, E);
  k_binC<<<NB, 256, 0, stream>>>(tmp, boff, off, esrc, N);

  // layer 1
  k_gemm<1, 0><<<gG, 256, 0, stream>>>(Xb, Pp1, nullptr, nullptr, bp1, Yb, N);
  k_gather_max<<<gRW, 256, 0, stream>>>(Yb, off, esrc, AGGb, N);
  k_gemm<2, 1><<<gG, 256, 0, stream>>>(Xb, Ps1, AGGb, Pn1, b1, Hb, N);

  // layer 2
  k_gemm<1, 0><<<gG, 256, 0, stream>>>(Hb, Pp2, nullptr, nullptr, bp2, Yb, N);
  k_gather_max<<<gRW, 256, 0, stream>>>(Yb, off, esrc, AGGb, N);
  k_gemm<2, 2><<<gG, 256, 0, stream>>>(Hb, Ps2, AGGb, Pn2, b2, out, N);
}

// Round 3
// 302.628 us; speedup vs baseline: 2.4474x; 1.1553x over previous
//
#include <hip/hip_runtime.h>
#include <hip/hip_bf16.h>

#define NF 128

typedef __attribute__((ext_vector_type(8))) short bf8;
typedef __attribute__((ext_vector_type(4))) float f4;

static __device__ __forceinline__ unsigned short f2bf(float f) {
  unsigned u = __builtin_bit_cast(unsigned, f);
  u = u + 0x7FFF + ((u >> 16) & 1);            // RNE
  return (unsigned short)(u >> 16);
}

// ---------------- fp32 -> bf16 convert (X), also zeroes bucket counters ----------------

__global__ void k_convX(const float* __restrict__ A, unsigned short* __restrict__ B,
                        long long nelem, int* __restrict__ bcnt, int nb) {
  long long i = (long long)(blockIdx.x * blockDim.x + threadIdx.x) * 8;
  if (blockIdx.x == 0 && (int)threadIdx.x < nb) bcnt[threadIdx.x] = 0;
  if (i + 8 > nelem) return;
  float4 a = *(const float4*)(A + i);
  float4 b = *(const float4*)(A + i + 4);
  uint4 o;
  o.x = f2bf(a.x) | ((unsigned)f2bf(a.y) << 16);
  o.y = f2bf(a.z) | ((unsigned)f2bf(a.w) << 16);
  o.z = f2bf(b.x) | ((unsigned)f2bf(b.y) << 16);
  o.w = f2bf(b.z) | ((unsigned)f2bf(b.w) << 16);
  *(uint4*)(B + i) = o;
}

// ---------------- pack 6 weight matrices [128][128] f32 -> B-fragment-ordered bf16 ----------------
// unit u = c*64 + lane, c = t*4+kk; elem j = W[kk*32 + (lane>>4)*8 + j][t*16 + (lane&15)]

__global__ void k_packW(const float* W0, const float* W1, const float* W2,
                        const float* W3, const float* W4, const float* W5,
                        unsigned short* __restrict__ out) {
  int gid = blockIdx.x * blockDim.x + threadIdx.x;
  int m = gid >> 11;
  int u = gid & 2047;
  if (m >= 6) return;
  const float* W = (m == 0) ? W0 : (m == 1) ? W1 : (m == 2) ? W2
                 : (m == 3) ? W3 : (m == 4) ? W4 : W5;
  int l = u & 63, c = u >> 6;
  int kk = c & 3, t = c >> 2;
  int kb = kk * 32 + ((l >> 4) << 3);
  int n = t * 16 + (l & 15);
  unsigned short* o = out + (size_t)m * 2048 * 8 + (size_t)u * 8;
  #pragma unroll
  for (int j = 0; j < 8; ++j) o[j] = f2bf(W[(size_t)(kb + j) * NF + n]);
}

// ---------------- CSR build: bucket(256 dsts) 2-pass sort ----------------

#define TILE_B 8192

__global__ __launch_bounds__(256) void k_bhist(const int* __restrict__ dst,
                                               int* __restrict__ bcnt, int E) {
  __shared__ int h[256];
  int tid = threadIdx.x;
  h[tid] = 0;
  __syncthreads();
  int t0 = blockIdx.x * TILE_B;
  int tend = min(E, t0 + TILE_B);
  for (int i = t0 + tid; i < tend; i += 256) atomicAdd(&h[dst[i] >> 8], 1);
  __syncthreads();
  if (h[tid] > 0) atomicAdd(&bcnt[tid], h[tid]);
}

__global__ __launch_bounds__(256) void k_bscan(const int* __restrict__ bcnt,
                                               int* __restrict__ boff,
                                               int* __restrict__ cursors,
                                               int* __restrict__ off,
                                               int nb, int N, int E) {
  __shared__ int sc[256];
  int tid = threadIdx.x;
  int v = (tid < nb) ? bcnt[tid] : 0;
  sc[tid] = v;
  __syncthreads();
  for (int d = 1; d < 256; d <<= 1) {
    int t = (tid >= d) ? sc[tid - d] : 0;
    __syncthreads();
    sc[tid] += t;
    __syncthreads();
  }
  if (tid < nb) {
    boff[tid + 1] = sc[tid];
    cursors[tid] = sc[tid] - v;
  }
  if (tid == 0) { boff[0] = 0; off[N] = E; }
}

// pass B: tile-local counting sort by bucket; bucket id kept in top 8 bits (src<2^16, NB<=256)
__global__ __launch_bounds__(256) void k_binB(const int* __restrict__ src,
                                              const int* __restrict__ dst,
                                              int* __restrict__ cursors,
                                              unsigned* __restrict__ tmp, int E) {
  __shared__ int h[256], sc[256], gb[256], lc[256];
  __shared__ unsigned sorted[TILE_B];
  int tid = threadIdx.x;
  int t0 = blockIdx.x * TILE_B;
  int tcnt = min(E - t0, TILE_B);
  if (tcnt <= 0) return;
  h[tid] = 0;
  __syncthreads();
  for (int i = tid; i < tcnt; i += 256) atomicAdd(&h[dst[t0 + i] >> 8], 1);
  __syncthreads();
  int v = h[tid];
  sc[tid] = v;
  __syncthreads();
  for (int d = 1; d < 256; d <<= 1) {
    int t = (tid >= d) ? sc[tid - d] : 0;
    __syncthreads();
    sc[tid] += t;
    __syncthreads();
  }
  lc[tid] = 0;
  gb[tid] = (v > 0) ? atomicAdd(&cursors[tid], v) : 0;
  __syncthreads();
  for (int i = tid; i < tcnt; i += 256) {
    int d = dst[t0 + i];
    unsigned s = (unsigned)src[t0 + i];
    int b = d >> 8;
    int p = (sc[b] - h[b]) + atomicAdd(&lc[b], 1);
    sorted[p] = ((unsigned)b << 24) | (s << 8) | (unsigned)(d & 255);
  }
  __syncthreads();
  for (int i = tid; i < tcnt; i += 256) {
    unsigned ev = sorted[i];
    int b = ev >> 24;
    tmp[gb[b] + (i - (sc[b] - h[b]))] = ev & 0xFFFFFFu;
  }
}

// pass C: per-bucket CSR in LDS, coalesced flush; also writes off[]
#define CSR_CAP 15360

__global__ __launch_bounds__(256) void k_binC(const unsigned* __restrict__ tmp,
                                              const int* __restrict__ boff,
                                              int* __restrict__ off,
                                              int* __restrict__ esrc, int N) {
  __shared__ int lh[256], ls[256], lcur[256];
  __shared__ int csr[CSR_CAP];
  int tid = threadIdx.x;
  int b = blockIdx.x;
  int base = b << 8;
  int beg = boff[b], end = boff[b + 1];
  int cnt = end - beg;
  lh[tid] = 0;
  __syncthreads();
  for (int i = beg + tid; i < end; i += 256) atomicAdd(&lh[tmp[i] & 255], 1);
  __syncthreads();
  int v = lh[tid];
  ls[tid] = v;
  __syncthreads();
  for (int d = 1; d < 256; d <<= 1) {
    int t = (tid >= d) ? ls[tid - d] : 0;
    __syncthreads();
    ls[tid] += t;
    __syncthreads();
  }
  int excl = ls[tid] - v;
  if (base + tid < N) off[base + tid] = beg + excl;
  lcur[tid] = 0;
  __syncthreads();
  if (cnt <= CSR_CAP) {
    for (int i = beg + tid; i < end; i += 256) {
      unsigned e = tmp[i];
      int dl = (int)(e & 255);
      int p = (ls[dl] - lh[dl]) + atomicAdd(&lcur[dl], 1);
      csr[p] = (int)(e >> 8);
    }
    __syncthreads();
    for (int i = tid; i < cnt; i += 256) esrc[beg + i] = csr[i];
  } else {
    for (int i = beg + tid; i < end; i += 256) {
      unsigned e = tmp[i];
      int dl = (int)(e & 255);
      int p = (ls[dl] - lh[dl]) + atomicAdd(&lcur[dl], 1);
      esrc[beg + p] = (int)(e >> 8);
    }
  }
}

// ---------------- MFMA GEMM: C = epilogue(A0@W0 [+ A1@W1] + bias) ----------------
// 256 thr = 4 waves; block = 64 rows x 128 cols; wave w -> rows w*16..w*16+15.
// W staged in LDS (reused as epilogue transpose buffer).
// OUT_MODE: 0 = relu -> bf16   1 = l2norm+relu -> bf16   2 = l2norm+relu -> fp32

template <int NMAT, int OUT_MODE>
__global__ __launch_bounds__(256) void k_gemm(
    const unsigned short* __restrict__ A0, const unsigned short* __restrict__ P0,
    const unsigned short* __restrict__ A1, const unsigned short* __restrict__ P1,
    const float* __restrict__ bias, void* __restrict__ Cout, int M) {
  __shared__ __align__(16) char smem[NMAT * 32768];
  int tid = threadIdx.x, w = tid >> 6, lane = tid & 63;
  int r0 = lane & 15, g = lane >> 4;
  int base = blockIdx.x * 64;
  int rowbase = base + w * 16;
  int arow = min(rowbase + r0, M - 1);

  // stage packed W into LDS
  {
    uint4* S = (uint4*)smem;
    const uint4* Pv0 = (const uint4*)P0;
    for (int t = tid; t < 2048; t += 256) S[t] = Pv0[t];
    if (NMAT == 2) {
      const uint4* Pv1 = (const uint4*)P1;
      for (int t = tid; t < 2048; t += 256) S[2048 + t] = Pv1[t];
    }
  }
  __syncthreads();

  f4 acc[8];
  #pragma unroll
  for (int t = 0; t < 8; ++t) acc[t] = (f4){0.f, 0.f, 0.f, 0.f};

  #pragma unroll
  for (int mat = 0; mat < NMAT; ++mat) {
    const unsigned short* A = (mat == 0) ? A0 : A1;
    const bf8* Ar = (const bf8*)(A + (size_t)arow * NF);
    const bf8* Wl = (const bf8*)smem + (size_t)mat * 2048;
    #pragma unroll
    for (int kk = 0; kk < 4; ++kk) {
      bf8 a = Ar[kk * 4 + g];
      #pragma unroll
      for (int t = 0; t < 8; ++t) {
        bf8 b = Wl[(t * 4 + kk) * 64 + lane];
        acc[t] = __builtin_amdgcn_mfma_f32_16x16x32_bf16(a, b, acc[t], 0, 0, 0);
      }
    }
  }

  float bb[8];
  #pragma unroll
  for (int t = 0; t < 8; ++t) bb[t] = bias[t * 16 + r0];

  float val[8][4];
  #pragma unroll
  for (int t = 0; t < 8; ++t)
    #pragma unroll
    for (int i = 0; i < 4; ++i) val[t][i] = acc[t][i] + bb[t];

  float inv[4] = {1.f, 1.f, 1.f, 1.f};
  if (OUT_MODE != 0) {
    float ss[4] = {0.f, 0.f, 0.f, 0.f};
    #pragma unroll
    for (int i = 0; i < 4; ++i)
      #pragma unroll
      for (int t = 0; t < 8; ++t) ss[i] += val[t][i] * val[t][i];
    #pragma unroll
    for (int d = 1; d < 16; d <<= 1)
      #pragma unroll
      for (int i = 0; i < 4; ++i) ss[i] += __shfl_xor(ss[i], d, 64);
    #pragma unroll
    for (int i = 0; i < 4; ++i) inv[i] = 1.f / fmaxf(sqrtf(ss[i]), 1e-12f);
  }

  __syncthreads();   // done reading W; reuse smem as output staging
  int maxrows = min(64, M - base);

  if (OUT_MODE == 2) {
    float* So = (float*)smem;   // 64x128 f32 = 32 KB (NMAT==2 here)
    #pragma unroll
    for (int i = 0; i < 4; ++i)
      #pragma unroll
      for (int t = 0; t < 8; ++t)
        So[(w * 16 + g * 4 + i) * NF + t * 16 + r0] = fmaxf(val[t][i] * inv[i], 0.f);
    __syncthreads();
    uint4* Og = (uint4*)((float*)Cout + (size_t)base * NF);
    const uint4* Sv = (const uint4*)smem;
    int maxc = maxrows * 32;
    for (int c = tid; c < 2048; c += 256)
      if (c < maxc) Og[c] = Sv[c];
  } else {
    unsigned short* So = (unsigned short*)smem;  // 64x128 bf16 = 16 KB
    #pragma unroll
    for (int i = 0; i < 4; ++i)
      #pragma unroll
      for (int t = 0; t < 8; ++t)
        So[(w * 16 + g * 4 + i) * NF + t * 16 + r0] =
            f2bf(fmaxf(val[t][i] * inv[i], 0.f));
    __syncthreads();
    uint4* Og = (uint4*)((unsigned short*)Cout + (size_t)base * NF);
    const uint4* Sv = (const uint4*)smem;
    int maxc = maxrows * 16;
    for (int c = tid; c < 1024; c += 256)
      if (c < maxc) Og[c] = Sv[c];
  }
}

// ---------------- gather-max over in-edges (bf16 rows), one wave per dst ----------------
// 64 edge indices block-loaded coalesced into lanes, broadcast via readlane; 8 rows in flight.

__global__ __launch_bounds__(256) void k_gather_max(
    const unsigned short* __restrict__ Y, const int* __restrict__ off,
    const int* __restrict__ esrc, unsigned short* __restrict__ AGG, int N) {
  int w = (blockIdx.x * 256 + threadIdx.x) >> 6;
  int lane = threadIdx.x & 63;
  if (w >= N) return;
  int s = __builtin_amdgcn_readfirstlane(off[w]);
  int e = __builtin_amdgcn_readfirstlane(off[w + 1]);
  float ax = 0.f, ay = 0.f;                 // relu output >= 0 -> 0 == empty fill
  for (int basei = s; basei < e; basei += 64) {
    int cnt = min(64, e - basei);
    int idxv = esrc[basei + min(lane, cnt - 1)];   // coalesced block load
    int i = 0;
    for (; i + 8 <= cnt; i += 8) {
      unsigned v[8];
      #pragma unroll
      for (int j = 0; j < 8; ++j) {
        int u = __builtin_amdgcn_readlane(idxv, i + j);
        v[j] = *((const unsigned*)(Y + (size_t)u * NF) + lane);
      }
      #pragma unroll
      for (int j = 0; j < 8; ++j) {
        ax = fmaxf(ax, __builtin_bit_cast(float, v[j] << 16));
        ay = fmaxf(ay, __builtin_bit_cast(float, v[j] & 0xFFFF0000u));
      }
    }
    for (; i < cnt; ++i) {
      int u = __builtin_amdgcn_readlane(idxv, i);
      unsigned v = *((const unsigned*)(Y + (size_t)u * NF) + lane);
      ax = fmaxf(ax, __builtin_bit_cast(float, v << 16));
      ay = fmaxf(ay, __builtin_bit_cast(float, v & 0xFFFF0000u));
    }
  }
  unsigned o = (unsigned)f2bf(ax) | ((unsigned)f2bf(ay) << 16);
  *(unsigned*)(AGG + (size_t)w * NF + lane * 2) = o;
}

// ---------------- launch ----------------

extern "C" void kernel_launch(void* const* d_in, const int* in_sizes, int n_in,
                              void* d_out, int out_size, void* d_ws, size_t ws_size,
                              hipStream_t stream) {
  const float* x   = (const float*)d_in[0];
  const int*   src = (const int*)d_in[1];
  const int*   dst = (const int*)d_in[2];
  const float* Wp1 = (const float*)d_in[3];
  const float* bp1 = (const float*)d_in[4];
  const float* Ws1 = (const float*)d_in[5];
  const float* Wn1 = (const float*)d_in[6];
  const float* b1  = (const float*)d_in[7];
  const float* Wp2 = (const float*)d_in[8];
  const float* bp2 = (const float*)d_in[9];
  const float* Ws2 = (const float*)d_in[10];
  const float* Wn2 = (const float*)d_in[11];
  const float* b2  = (const float*)d_in[12];
  float* out = (float*)d_out;

  const int N = in_sizes[0] / NF;
  const int E = in_sizes[1];
  const int NB = (N + 255) >> 8;

  char* ws = (char*)d_ws;
  auto carve = [&](size_t bytes) { char* p = ws; ws += (bytes + 255) & ~(size_t)255; return p; };
  unsigned short* Xb    = (unsigned short*)carve((size_t)N * NF * 2);
  unsigned short* Yb    = (unsigned short*)carve((size_t)N * NF * 2);
  unsigned short* AGGb  = (unsigned short*)carve((size_t)N * NF * 2);
  unsigned short* Hb    = (unsigned short*)carve((size_t)N * NF * 2);
  unsigned short* Wpack = (unsigned short*)carve((size_t)6 * NF * NF * 2);
  int* off     = (int*)carve((size_t)(N + 1) * 4);
  int* bcnt    = (int*)carve((size_t)NB * 4);
  int* boff    = (int*)carve((size_t)(NB + 1) * 4);
  int* cursors = (int*)carve((size_t)NB * 4);
  unsigned* tmp = (unsigned*)carve((size_t)E * 4);
  int* esrc    = (int*)carve((size_t)E * 4);

  unsigned short* Pp1 = Wpack + 0 * NF * NF;
  unsigned short* Ps1 = Wpack + 1 * NF * NF;
  unsigned short* Pn1 = Wpack + 2 * NF * NF;
  unsigned short* Pp2 = Wpack + 3 * NF * NF;
  unsigned short* Ps2 = Wpack + 4 * NF * NF;
  unsigned short* Pn2 = Wpack + 5 * NF * NF;

  const long long nelX = (long long)N * NF;
  const int gConv = (int)((nelX / 8 + 255) / 256);
  const int gPack = (6 * 2048 + 255) / 256;
  const int gTile = (E + TILE_B - 1) / TILE_B;
  const int gG    = (N + 63) / 64;
  const int gRW   = (N + 3) / 4;

  k_convX<<<gConv, 256, 0, stream>>>(x, Xb, nelX, bcnt, NB);
  k_packW<<<gPack, 256, 0, stream>>>(Wp1, Ws1, Wn1, Wp2, Ws2, Wn2, Wpack);

  k_bhist<<<gTile, 256, 0, stream>>>(dst, bcnt, E);
  k_bscan<<<1, 256, 0, stream>>>(bcnt, boff, cursors, off, NB, N, E);
  k_binB<<<gTile, 256, 0, stream>>>(src, dst, cursors, tmp, E);
  k_binC<<<NB, 256, 0, stream>>>(tmp, boff, off, esrc, N);

  k_gemm<1, 0><<<gG, 256, 0, stream>>>(Xb, Pp1, nullptr, nullptr, bp1, Yb, N);
  k_gather_max<<<gRW, 256, 0, stream>>>(Yb, off, esrc, AGGb, N);
  k_gemm<2, 1><<<gG, 256, 0, stream>>>(Xb, Ps1, AGGb, Pn1, b1, Hb, N);

  k_gemm<1, 0><<<gG, 256, 0, stream>>>(Hb, Pp2, nullptr, nullptr, bp2, Yb, N);
  k_gather_max<<<gRW, 256, 0, stream>>>(Yb, off, esrc, AGGb, N);
  k_gemm<2, 2><<<gG, 256, 0, stream>>>(Hb, Ps2, AGGb, Pn2, b2, out, N);
}

// Round 4
// 290.958 us; speedup vs baseline: 2.5455x; 1.0401x over previous
//
#include <hip/hip_runtime.h>
#include <hip/hip_bf16.h>

#define NF 128

typedef __attribute__((ext_vector_type(8))) short bf8;
typedef __attribute__((ext_vector_type(4))) float f4;
typedef unsigned short u16x8 __attribute__((ext_vector_type(8)));

static __device__ __forceinline__ unsigned short f2bf(float f) {
  unsigned u = __builtin_bit_cast(unsigned, f);
  u = u + 0x7FFF + ((u >> 16) & 1);            // RNE
  return (unsigned short)(u >> 16);
}

static __device__ __forceinline__ uint4 pkmax4(uint4 a, uint4 b) {
  u16x8 x = __builtin_bit_cast(u16x8, a);
  u16x8 y = __builtin_bit_cast(u16x8, b);
  u16x8 m = __builtin_elementwise_max(x, y);   // v_pk_max_u16: valid for relu'd bf16 (>=0)
  return __builtin_bit_cast(uint4, m);
}

static __device__ __forceinline__ uint4 shflxor4(uint4 a, int m) {
  uint4 r;
  r.x = (unsigned)__shfl_xor((int)a.x, m, 64);
  r.y = (unsigned)__shfl_xor((int)a.y, m, 64);
  r.z = (unsigned)__shfl_xor((int)a.z, m, 64);
  r.w = (unsigned)__shfl_xor((int)a.w, m, 64);
  return r;
}

// ---------------- fp32 -> bf16 convert (X), also zeroes bucket counters ----------------

__global__ void k_convX(const float* __restrict__ A, unsigned short* __restrict__ B,
                        long long nelem, int* __restrict__ bcnt, int nb) {
  long long i = (long long)(blockIdx.x * blockDim.x + threadIdx.x) * 8;
  if (blockIdx.x == 0 && (int)threadIdx.x < nb) bcnt[threadIdx.x] = 0;
  if (i + 8 > nelem) return;
  float4 a = *(const float4*)(A + i);
  float4 b = *(const float4*)(A + i + 4);
  uint4 o;
  o.x = f2bf(a.x) | ((unsigned)f2bf(a.y) << 16);
  o.y = f2bf(a.z) | ((unsigned)f2bf(a.w) << 16);
  o.z = f2bf(b.x) | ((unsigned)f2bf(b.y) << 16);
  o.w = f2bf(b.z) | ((unsigned)f2bf(b.w) << 16);
  *(uint4*)(B + i) = o;
}

// ---------------- pack 6 weight matrices [128][128] f32 -> B-fragment-ordered bf16 ----------------
// unit u = c*64 + lane, c = t*4+kk; elem j = W[kk*32 + (lane>>4)*8 + j][t*16 + (lane&15)]

__global__ void k_packW(const float* W0, const float* W1, const float* W2,
                        const float* W3, const float* W4, const float* W5,
                        unsigned short* __restrict__ out) {
  int gid = blockIdx.x * blockDim.x + threadIdx.x;
  int m = gid >> 11;
  int u = gid & 2047;
  if (m >= 6) return;
  const float* W = (m == 0) ? W0 : (m == 1) ? W1 : (m == 2) ? W2
                 : (m == 3) ? W3 : (m == 4) ? W4 : W5;
  int l = u & 63, c = u >> 6;
  int kk = c & 3, t = c >> 2;
  int kb = kk * 32 + ((l >> 4) << 3);
  int n = t * 16 + (l & 15);
  unsigned short* o = out + (size_t)m * 2048 * 8 + (size_t)u * 8;
  #pragma unroll
  for (int j = 0; j < 8; ++j) o[j] = f2bf(W[(size_t)(kb + j) * NF + n]);
}

// ---------------- CSR build: bucket(256 dsts) 2-pass sort ----------------

#define TILE_B 8192

__global__ __launch_bounds__(256) void k_bhist(const int* __restrict__ dst,
                                               int* __restrict__ bcnt, int E) {
  __shared__ int h[256];
  int tid = threadIdx.x;
  h[tid] = 0;
  __syncthreads();
  int t0 = blockIdx.x * TILE_B;
  int tend = min(E, t0 + TILE_B);
  for (int i = t0 + tid; i < tend; i += 256) atomicAdd(&h[dst[i] >> 8], 1);
  __syncthreads();
  if (h[tid] > 0) atomicAdd(&bcnt[tid], h[tid]);
}

__global__ __launch_bounds__(256) void k_bscan(const int* __restrict__ bcnt,
                                               int* __restrict__ boff,
                                               int* __restrict__ cursors,
                                               int* __restrict__ off,
                                               int nb, int N, int E) {
  __shared__ int sc[256];
  int tid = threadIdx.x;
  int v = (tid < nb) ? bcnt[tid] : 0;
  sc[tid] = v;
  __syncthreads();
  for (int d = 1; d < 256; d <<= 1) {
    int t = (tid >= d) ? sc[tid - d] : 0;
    __syncthreads();
    sc[tid] += t;
    __syncthreads();
  }
  if (tid < nb) {
    boff[tid + 1] = sc[tid];
    cursors[tid] = sc[tid] - v;
  }
  if (tid == 0) { boff[0] = 0; off[N] = E; }
}

// pass B: tile-local counting sort by bucket; bucket id in top 8 bits (src<2^16, NB<=256)
__global__ __launch_bounds__(256) void k_binB(const int* __restrict__ src,
                                              const int* __restrict__ dst,
                                              int* __restrict__ cursors,
                                              unsigned* __restrict__ tmp, int E) {
  __shared__ int h[256], sc[256], gb[256], lc[256];
  __shared__ unsigned sorted[TILE_B];
  int tid = threadIdx.x;
  int t0 = blockIdx.x * TILE_B;
  int tcnt = min(E - t0, TILE_B);
  if (tcnt <= 0) return;
  h[tid] = 0;
  __syncthreads();
  for (int i = tid; i < tcnt; i += 256) atomicAdd(&h[dst[t0 + i] >> 8], 1);
  __syncthreads();
  int v = h[tid];
  sc[tid] = v;
  __syncthreads();
  for (int d = 1; d < 256; d <<= 1) {
    int t = (tid >= d) ? sc[tid - d] : 0;
    __syncthreads();
    sc[tid] += t;
    __syncthreads();
  }
  lc[tid] = 0;
  gb[tid] = (v > 0) ? atomicAdd(&cursors[tid], v) : 0;
  __syncthreads();
  for (int i = tid; i < tcnt; i += 256) {
    int d = dst[t0 + i];
    unsigned s = (unsigned)src[t0 + i];
    int b = d >> 8;
    int p = (sc[b] - h[b]) + atomicAdd(&lc[b], 1);
    sorted[p] = ((unsigned)b << 24) | (s << 8) | (unsigned)(d & 255);
  }
  __syncthreads();
  for (int i = tid; i < tcnt; i += 256) {
    unsigned ev = sorted[i];
    int b = ev >> 24;
    tmp[gb[b] + (i - (sc[b] - h[b]))] = ev & 0xFFFFFFu;
  }
}

// pass C: per-bucket CSR in LDS, coalesced flush; writes off[] and ushort esrc
#define CSR_CAP 15360

__global__ __launch_bounds__(256) void k_binC(const unsigned* __restrict__ tmp,
                                              const int* __restrict__ boff,
                                              int* __restrict__ off,
                                              unsigned short* __restrict__ esrc, int N) {
  __shared__ int lh[256], ls[256], lcur[256];
  __shared__ int csr[CSR_CAP];
  int tid = threadIdx.x;
  int b = blockIdx.x;
  int base = b << 8;
  int beg = boff[b], end = boff[b + 1];
  int cnt = end - beg;
  lh[tid] = 0;
  __syncthreads();
  for (int i = beg + tid; i < end; i += 256) atomicAdd(&lh[tmp[i] & 255], 1);
  __syncthreads();
  int v = lh[tid];
  ls[tid] = v;
  __syncthreads();
  for (int d = 1; d < 256; d <<= 1) {
    int t = (tid >= d) ? ls[tid - d] : 0;
    __syncthreads();
    ls[tid] += t;
    __syncthreads();
  }
  int excl = ls[tid] - v;
  if (base + tid < N) off[base + tid] = beg + excl;
  lcur[tid] = 0;
  __syncthreads();
  if (cnt <= CSR_CAP) {
    for (int i = beg + tid; i < end; i += 256) {
      unsigned e = tmp[i];
      int dl = (int)(e & 255);
      int p = (ls[dl] - lh[dl]) + atomicAdd(&lcur[dl], 1);
      csr[p] = (int)(e >> 8);
    }
    __syncthreads();
    for (int i = tid; i < cnt; i += 256) esrc[beg + i] = (unsigned short)csr[i];
  } else {
    for (int i = beg + tid; i < end; i += 256) {
      unsigned e = tmp[i];
      int dl = (int)(e & 255);
      int p = (ls[dl] - lh[dl]) + atomicAdd(&lcur[dl], 1);
      esrc[beg + p] = (unsigned short)(e >> 8);
    }
  }
}

// ---------------- pool GEMM: Y = relu(A@W + b), W staged in LDS, coalesced store ----------------

__global__ __launch_bounds__(256) void k_gemm_pool(
    const unsigned short* __restrict__ A, const unsigned short* __restrict__ P,
    const float* __restrict__ bias, unsigned short* __restrict__ Yout, int M) {
  __shared__ __align__(16) char smem[32768];
  int tid = threadIdx.x, w = tid >> 6, lane = tid & 63;
  int r0 = lane & 15, g = lane >> 4;
  int base = blockIdx.x * 64;
  int arow = min(base + w * 16 + r0, M - 1);

  {
    uint4* S = (uint4*)smem;
    const uint4* Pv = (const uint4*)P;
    for (int t = tid; t < 2048; t += 256) S[t] = Pv[t];
  }
  __syncthreads();

  f4 acc[8];
  #pragma unroll
  for (int t = 0; t < 8; ++t) acc[t] = (f4){0.f, 0.f, 0.f, 0.f};

  const bf8* Ar = (const bf8*)(A + (size_t)arow * NF);
  const bf8* Wl = (const bf8*)smem;
  #pragma unroll
  for (int kk = 0; kk < 4; ++kk) {
    bf8 a = Ar[kk * 4 + g];
    #pragma unroll
    for (int t = 0; t < 8; ++t) {
      bf8 b = Wl[(t * 4 + kk) * 64 + lane];
      acc[t] = __builtin_amdgcn_mfma_f32_16x16x32_bf16(a, b, acc[t], 0, 0, 0);
    }
  }

  float bb[8];
  #pragma unroll
  for (int t = 0; t < 8; ++t) bb[t] = bias[t * 16 + r0];

  __syncthreads();
  unsigned short* So = (unsigned short*)smem;   // 64x128 bf16 = 16 KB
  #pragma unroll
  for (int i = 0; i < 4; ++i)
    #pragma unroll
    for (int t = 0; t < 8; ++t)
      So[(w * 16 + g * 4 + i) * NF + t * 16 + r0] = f2bf(fmaxf(acc[t][i] + bb[t], 0.f));
  __syncthreads();
  int maxrows = min(64, M - base);
  uint4* Og = (uint4*)(Yout + (size_t)base * NF);
  const uint4* Sv = (const uint4*)smem;
  int maxc = maxrows * 16;
  for (int c = tid; c < 1024; c += 256)
    if (c < maxc) Og[c] = Sv[c];
}

// ---------------- fused: gather-max (into LDS) + dual GEMM + l2norm + relu ----------------
// block = 64 dst nodes; wave w gathers nodes base+w*16..+15, then MFMA on same rows.
// OUT_MODE: 1 = bf16 out, 2 = fp32 out

template <int OUT_MODE>
__global__ __launch_bounds__(256) void k_fused(
    const unsigned short* __restrict__ Y, const int* __restrict__ off,
    const unsigned short* __restrict__ esrc,
    const unsigned short* __restrict__ X,
    const unsigned short* __restrict__ Pself, const unsigned short* __restrict__ Pneigh,
    const float* __restrict__ bias, void* __restrict__ Cout, int M) {
  constexpr int SMEM = (OUT_MODE == 2) ? 32768 : 17408;
  __shared__ __align__(16) char smem[SMEM];
  unsigned short (*agg)[136] = (unsigned short (*)[136])smem;   // 272 B rows: 2-way banks max

  int tid = threadIdx.x, w = tid >> 6, lane = tid & 63;
  int r0 = lane & 15, g = lane >> 4;
  int base = blockIdx.x * 64;

  // ---- gather phase ----
  for (int n = 0; n < 16; ++n) {
    int node = base + w * 16 + n;
    uint4 am = {0u, 0u, 0u, 0u};                   // relu >= 0 -> 0 == empty fill
    if (node < M) {
      int s = __builtin_amdgcn_readfirstlane(off[node]);
      int e = __builtin_amdgcn_readfirstlane(off[node + 1]);
      for (int b0 = s; b0 < e; b0 += 64) {
        int cnt = min(64, e - b0);
        int idxv = (int)esrc[b0 + min(lane, cnt - 1)];   // coalesced ushort block load
        for (int i = 0; i < cnt; i += 16) {
          #pragma unroll
          for (int j = 0; j < 4; ++j) {                  // 4 edges per dwordx4 instr
            int eo = min(i + j * 4 + g, cnt - 1);
            int u = __shfl(idxv, eo, 64);
            uint4 v = *((const uint4*)(Y + (size_t)u * NF) + r0);
            am = pkmax4(am, v);
          }
        }
      }
      am = pkmax4(am, shflxor4(am, 16));
      am = pkmax4(am, shflxor4(am, 32));
    }
    if (g == 0) *(uint4*)&agg[w * 16 + n][r0 * 8] = am;
  }
  __syncthreads();

  // ---- dual GEMM ----
  int arow = min(base + w * 16 + r0, M - 1);
  f4 acc[8];
  #pragma unroll
  for (int t = 0; t < 8; ++t) acc[t] = (f4){0.f, 0.f, 0.f, 0.f};

  const bf8* Ar = (const bf8*)(X + (size_t)arow * NF);
  const bf8* Bs = (const bf8*)Pself;
  #pragma unroll
  for (int kk = 0; kk < 4; ++kk) {
    bf8 a = Ar[kk * 4 + g];
    #pragma unroll
    for (int t = 0; t < 8; ++t)
      acc[t] = __builtin_amdgcn_mfma_f32_16x16x32_bf16(a, Bs[(t * 4 + kk) * 64 + lane], acc[t], 0, 0, 0);
  }
  const bf8* Bn = (const bf8*)Pneigh;
  #pragma unroll
  for (int kk = 0; kk < 4; ++kk) {
    bf8 a = *(const bf8*)&agg[w * 16 + r0][kk * 32 + g * 8];
    #pragma unroll
    for (int t = 0; t < 8; ++t)
      acc[t] = __builtin_amdgcn_mfma_f32_16x16x32_bf16(a, Bn[(t * 4 + kk) * 64 + lane], acc[t], 0, 0, 0);
  }

  float bb[8];
  #pragma unroll
  for (int t = 0; t < 8; ++t) bb[t] = bias[t * 16 + r0];

  float val[8][4];
  #pragma unroll
  for (int t = 0; t < 8; ++t)
    #pragma unroll
    for (int i = 0; i < 4; ++i) val[t][i] = acc[t][i] + bb[t];

  float ss[4] = {0.f, 0.f, 0.f, 0.f};
  #pragma unroll
  for (int i = 0; i < 4; ++i)
    #pragma unroll
    for (int t = 0; t < 8; ++t) ss[i] += val[t][i] * val[t][i];
  #pragma unroll
  for (int d = 1; d < 16; d <<= 1)
    #pragma unroll
    for (int i = 0; i < 4; ++i) ss[i] += __shfl_xor(ss[i], d, 64);
  float inv[4];
  #pragma unroll
  for (int i = 0; i < 4; ++i) inv[i] = 1.f / fmaxf(sqrtf(ss[i]), 1e-12f);

  __syncthreads();                     // agg dead; reuse smem for output staging
  int maxrows = min(64, M - base);

  if (OUT_MODE == 2) {
    float* So = (float*)smem;
    #pragma unroll
    for (int i = 0; i < 4; ++i)
      #pragma unroll
      for (int t = 0; t < 8; ++t)
        So[(w * 16 + g * 4 + i) * NF + t * 16 + r0] = fmaxf(val[t][i] * inv[i], 0.f);
    __syncthreads();
    uint4* Og = (uint4*)((float*)Cout + (size_t)base * NF);
    const uint4* Sv = (const uint4*)smem;
    int maxc = maxrows * 32;
    for (int c = tid; c < 2048; c += 256)
      if (c < maxc) Og[c] = Sv[c];
  } else {
    unsigned short* So = (unsigned short*)smem;
    #pragma unroll
    for (int i = 0; i < 4; ++i)
      #pragma unroll
      for (int t = 0; t < 8; ++t)
        So[(w * 16 + g * 4 + i) * NF + t * 16 + r0] = f2bf(fmaxf(val[t][i] * inv[i], 0.f));
    __syncthreads();
    uint4* Og = (uint4*)((unsigned short*)Cout + (size_t)base * NF);
    const uint4* Sv = (const uint4*)smem;
    int maxc = maxrows * 16;
    for (int c = tid; c < 1024; c += 256)
      if (c < maxc) Og[c] = Sv[c];
  }
}

// ---------------- launch ----------------

extern "C" void kernel_launch(void* const* d_in, const int* in_sizes, int n_in,
                              void* d_out, int out_size, void* d_ws, size_t ws_size,
                              hipStream_t stream) {
  const float* x   = (const float*)d_in[0];
  const int*   src = (const int*)d_in[1];
  const int*   dst = (const int*)d_in[2];
  const float* Wp1 = (const float*)d_in[3];
  const float* bp1 = (const float*)d_in[4];
  const float* Ws1 = (const float*)d_in[5];
  const float* Wn1 = (const float*)d_in[6];
  const float* b1  = (const float*)d_in[7];
  const float* Wp2 = (const float*)d_in[8];
  const float* bp2 = (const float*)d_in[9];
  const float* Ws2 = (const float*)d_in[10];
  const float* Wn2 = (const float*)d_in[11];
  const float* b2  = (const float*)d_in[12];
  float* out = (float*)d_out;

  const int N = in_sizes[0] / NF;
  const int E = in_sizes[1];
  const int NB = (N + 255) >> 8;

  char* ws = (char*)d_ws;
  auto carve = [&](size_t bytes) { char* p = ws; ws += (bytes + 255) & ~(size_t)255; return p; };
  unsigned short* Xb    = (unsigned short*)carve((size_t)N * NF * 2);
  unsigned short* Yb    = (unsigned short*)carve((size_t)N * NF * 2);
  unsigned short* Hb    = (unsigned short*)carve((size_t)N * NF * 2);
  unsigned short* Wpack = (unsigned short*)carve((size_t)6 * NF * NF * 2);
  int* off     = (int*)carve((size_t)(N + 1) * 4);
  int* bcnt    = (int*)carve((size_t)NB * 4);
  int* boff    = (int*)carve((size_t)(NB + 1) * 4);
  int* cursors = (int*)carve((size_t)NB * 4);
  unsigned* tmp = (unsigned*)carve((size_t)E * 4);
  unsigned short* esrc = (unsigned short*)carve((size_t)E * 2);

  unsigned short* Pp1 = Wpack + 0 * NF * NF;
  unsigned short* Ps1 = Wpack + 1 * NF * NF;
  unsigned short* Pn1 = Wpack + 2 * NF * NF;
  unsigned short* Pp2 = Wpack + 3 * NF * NF;
  unsigned short* Ps2 = Wpack + 4 * NF * NF;
  unsigned short* Pn2 = Wpack + 5 * NF * NF;

  const long long nelX = (long long)N * NF;
  const int gConv = (int)((nelX / 8 + 255) / 256);
  const int gPack = (6 * 2048 + 255) / 256;
  const int gTile = (E + TILE_B - 1) / TILE_B;
  const int gG    = (N + 63) / 64;

  k_convX<<<gConv, 256, 0, stream>>>(x, Xb, nelX, bcnt, NB);
  k_packW<<<gPack, 256, 0, stream>>>(Wp1, Ws1, Wn1, Wp2, Ws2, Wn2, Wpack);

  k_bhist<<<gTile, 256, 0, stream>>>(dst, bcnt, E);
  k_bscan<<<1, 256, 0, stream>>>(bcnt, boff, cursors, off, NB, N, E);
  k_binB<<<gTile, 256, 0, stream>>>(src, dst, cursors, tmp, E);
  k_binC<<<NB, 256, 0, stream>>>(tmp, boff, off, esrc, N);

  k_gemm_pool<<<gG, 256, 0, stream>>>(Xb, Pp1, bp1, Yb, N);
  k_fused<1><<<gG, 256, 0, stream>>>(Yb, off, esrc, Xb, Ps1, Pn1, b1, Hb, N);

  k_gemm_pool<<<gG, 256, 0, stream>>>(Hb, Pp2, bp2, Yb, N);
  k_fused<2><<<gG, 256, 0, stream>>>(Yb, off, esrc, Hb, Ps2, Pn2, b2, out, N);
}